// Round 7
// baseline (49.963 us; speedup 1.0000x reference)
//
#include <hip/hip_runtime.h>

// Problem constants (match reference)
#define BATCH 4
#define QLEN 2048
#define CLEN 2048
#define DIM 512
#define NBLK 512            // K1 blocks (2/CU -> all co-resident, no deadlock)
#define CPB 128             // chunks per batch
#define RPC 16              // context rows per chunk
#define NMID 32             // middle slice blocks (last finishers)
#define QSCALE 16777216.0f  // 2^24 fixed-point scale for deterministic i64 atomics
#define IQS (1.0f / QSCALE)

// The reference collapses: einsum 'bqkh,bvha->bqha' has independent k and v,
// and softmax over k sums to exactly 1, so
//   out[b,q,:] = ((sum_cl context[b,cl,:]) @ Wkv[:,D:2D]) @ Wout   for every q.
// query, Wq, mask are dead inputs.
//
// 2-kernel structure. K1 fuses colsum + both matvecs via int64 fixed-point
// atomics (deterministic) + last-finisher blocks (no fences: round-3/4 showed
// per-block __threadfence costs 100s of us; atomic RMW/loads are L2-coherent).

__device__ __forceinline__ unsigned ld_acq(unsigned* p) {
    return __hip_atomic_load(p, __ATOMIC_ACQUIRE, __HIP_MEMORY_SCOPE_AGENT);
}

__global__ __launch_bounds__(256) void k1_fused(
    const float* __restrict__ ctx, const float* __restrict__ Wkv,
    const float* __restrict__ Wout, unsigned long long* __restrict__ csum_i,
    float* __restrict__ vsum, float* __restrict__ orow, unsigned* __restrict__ ctr)
{
    __shared__ float4 red4[256];
    __shared__ float cs[DIM];      // csum slice (then reused for vsum)
    __shared__ float rr[512];      // float2 partial reduce
    __shared__ unsigned s_old;
    const int blk = blockIdx.x, t = threadIdx.x;
    const int b = blk >> 7, ch = blk & 127;

    // ---- Phase A (all blocks): colsum of 16 rows -> i64 atomic csum ----
    {
        const int rg = t >> 7, f4 = t & 127;
        const float4* src = reinterpret_cast<const float4*>(ctx)
                          + (size_t)(b * CLEN + ch * RPC) * (DIM / 4);
        float4 s = make_float4(0.f, 0.f, 0.f, 0.f);
#pragma unroll
        for (int i = 0; i < 8; ++i) {
            float4 x = src[(size_t)(rg + 2 * i) * (DIM / 4) + f4];
            s.x += x.x; s.y += x.y; s.z += x.z; s.w += x.w;
        }
        red4[t] = s;
        __syncthreads();
        if (t < 128) {
            float4 a = red4[t], c = red4[t + 128];
            unsigned long long* base = &csum_i[b * DIM + t * 4];
            atomicAdd(&base[0], (unsigned long long)(long long)llrintf((a.x + c.x) * QSCALE));
            atomicAdd(&base[1], (unsigned long long)(long long)llrintf((a.y + c.y) * QSCALE));
            atomicAdd(&base[2], (unsigned long long)(long long)llrintf((a.z + c.z) * QSCALE));
            atomicAdd(&base[3], (unsigned long long)(long long)llrintf((a.w + c.w) * QSCALE));
        }
        __syncthreads();   // drains vmcnt -> all block atomics complete at L2
        if (t == 0)
            s_old = __hip_atomic_fetch_add(&ctr[0], 1u, __ATOMIC_ACQ_REL,
                                           __HIP_MEMORY_SCOPE_AGENT);
        __syncthreads();
    }
    const unsigned old = s_old;
    if (old < NBLK - NMID) return;          // not a last-finisher: done
    const int m  = (int)old - (NBLK - NMID);   // slice 0..31
    const int b1 = m >> 3, sl = m & 7;         // batch, e/f slice

    // ---- Phase B (32 blocks): vsum[b1][sl*64 .. +64) ----
    if (t == 0) while (ld_acq(&ctr[0]) < NBLK) __builtin_amdgcn_s_sleep(2);
    __syncthreads();
    for (int j = t; j < DIM; j += 256) {
        long long q = (long long)__hip_atomic_load(&csum_i[b1 * DIM + j],
                          __ATOMIC_RELAXED, __HIP_MEMORY_SCOPE_AGENT);
        cs[j] = (float)q * IQS;
    }
    __syncthreads();
    {
        const int ep = t & 31, dg = t >> 5;    // e-pair, d-group
        const float* w = Wkv + (size_t)(dg * 64) * (2 * DIM) + DIM + sl * 64 + 2 * ep;
        float ax = 0.f, ay = 0.f;
#pragma unroll 8
        for (int i = 0; i < 64; ++i) {
            float c = cs[dg * 64 + i];
            float2 wv = *reinterpret_cast<const float2*>(&w[(size_t)i * (2 * DIM)]);
            ax += c * wv.x; ay += c * wv.y;
        }
        rr[t * 2] = ax; rr[t * 2 + 1] = ay;
    }
    __syncthreads();
    if (t < 32) {
        float ax = 0.f, ay = 0.f;
#pragma unroll
        for (int g = 0; g < 8; ++g) { ax += rr[(g * 32 + t) * 2]; ay += rr[(g * 32 + t) * 2 + 1]; }
        const int e2 = b1 * DIM + sl * 64 + 2 * t;
        __hip_atomic_store(&vsum[e2],     ax, __ATOMIC_RELAXED, __HIP_MEMORY_SCOPE_AGENT);
        __hip_atomic_store(&vsum[e2 + 1], ay, __ATOMIC_RELAXED, __HIP_MEMORY_SCOPE_AGENT);
    }
    __syncthreads();   // drain stores
    if (t == 0) __hip_atomic_fetch_add(&ctr[1], 1u, __ATOMIC_ACQ_REL,
                                       __HIP_MEMORY_SCOPE_AGENT);

    // ---- Phase C (32 blocks): orow[b1][sl*64 .. +64) ----
    if (t == 0) while (ld_acq(&ctr[1]) < NMID) __builtin_amdgcn_s_sleep(2);
    __syncthreads();
    for (int j = t; j < DIM; j += 256)
        cs[j] = __hip_atomic_load(&vsum[b1 * DIM + j], __ATOMIC_RELAXED,
                                  __HIP_MEMORY_SCOPE_AGENT);
    __syncthreads();
    {
        const int fp = t & 31, eg = t >> 5;    // f-pair, e-group
        const float* w = Wout + (size_t)(eg * 64) * DIM + sl * 64 + 2 * fp;
        float ax = 0.f, ay = 0.f;
#pragma unroll 8
        for (int i = 0; i < 64; ++i) {
            float v = cs[eg * 64 + i];
            float2 wv = *reinterpret_cast<const float2*>(&w[(size_t)i * DIM]);
            ax += v * wv.x; ay += v * wv.y;
        }
        rr[t * 2] = ax; rr[t * 2 + 1] = ay;
    }
    __syncthreads();
    if (t < 32) {
        float ax = 0.f, ay = 0.f;
#pragma unroll
        for (int g = 0; g < 8; ++g) { ax += rr[(g * 32 + t) * 2]; ay += rr[(g * 32 + t) * 2 + 1]; }
        orow[b1 * DIM + sl * 64 + 2 * t]     = ax;   // kernel-boundary flush -> visible to K2
        orow[b1 * DIM + sl * 64 + 2 * t + 1] = ay;
    }
}

// ---- K2: out[b,q,:] = orow[b,:] for all q (16.8 MB HBM write) ----
__global__ __launch_bounds__(256) void k2_bcast(const float4* __restrict__ orow4,
                                                float4* __restrict__ out) {
    const int blk = blockIdx.x, t = threadIdx.x;
    const int b = blk >> 8, qg = blk & 255;
    const int rg = t >> 7, f4 = t & 127;
    const float4 val = orow4[b * (DIM / 4) + f4];   // L2-hot
    float4* dst = out + (size_t)(b * QLEN + qg * 8) * (DIM / 4);
#pragma unroll
    for (int i = 0; i < 4; ++i)
        dst[(size_t)(rg + 2 * i) * (DIM / 4) + f4] = val;
}

extern "C" void kernel_launch(void* const* d_in, const int* in_sizes, int n_in,
                              void* d_out, int out_size, void* d_ws, size_t ws_size,
                              hipStream_t stream) {
    // inputs: 0=query (unused), 1=context, 2=mask (unused), 3=Wq (unused), 4=Wkv, 5=Wout
    const float* ctx  = (const float*)d_in[1];
    const float* Wkv  = (const float*)d_in[4];
    const float* Wout = (const float*)d_in[5];
    unsigned* ctr = (unsigned*)d_ws;                                  // 64 B
    unsigned long long* csum_i = (unsigned long long*)((char*)d_ws + 64);  // 16 KB
    float* vsum = (float*)((char*)d_ws + 64 + 16384);                 // 8 KB
    float* orow = vsum + BATCH * DIM;                                 // 8 KB

    // counters + csum accumulators must be zero EVERY call
    hipMemsetAsync(d_ws, 0, 64 + 16384, stream);
    k1_fused<<<NBLK, 256, 0, stream>>>(ctx, Wkv, Wout, csum_i, vsum, orow, ctr);
    k2_bcast<<<BATCH * 256, 256, 0, stream>>>((const float4*)orow, (float4*)d_out);
}

// Round 8
// 26.753 us; speedup vs baseline: 1.8676x; 1.8676x over previous
//
#include <hip/hip_runtime.h>

// Problem constants (match reference)
#define BATCH 4
#define QLEN 2048
#define CLEN 2048
#define DIM 512
#define NBLK1 512           // K1 blocks: b(4) x ch(128)
#define CPB 128             // chunks per batch
#define RPC 16              // context rows per chunk
#define NSL 8               // e-slices (64 e's each) in the middle kernel

// The reference collapses: einsum 'bqkh,bvha->bqha' has independent k and v,
// and softmax over k sums to exactly 1, so
//   out[b,q,:] = ((sum_cl context[b,cl,:]) @ Wkv[:,D:2D]) @ Wout   for every q.
// query, Wq, mask are dead inputs.
//
// 3 kernels, 2 boundaries. Every in-kernel grid-sync flavor measured 10-50x
// worse than a kernel boundary on this chip (rounds 3/4/7: 313/258/44 us).
// Trick: orow = sum_sl vsum[slice sl] @ Wout[sl,:] -- the middle kernel emits
// per-slice orow contributions, so no cross-block dependency inside it.

// ---- K1: partial[b][ch][d] = colsum of 16 context rows (16.8 MB read) ----
__global__ __launch_bounds__(256) void k1_partial(const float* __restrict__ ctx,
                                                  float4* __restrict__ partial) {
    __shared__ float4 red[256];
    const int blk = blockIdx.x, t = threadIdx.x;
    const int b = blk >> 7, ch = blk & 127;
    const int rg = t >> 7, f4 = t & 127;
    const float4* src = reinterpret_cast<const float4*>(ctx)
                      + (size_t)(b * CLEN + ch * RPC) * (DIM / 4);
    float4 s = make_float4(0.f, 0.f, 0.f, 0.f);
#pragma unroll
    for (int i = 0; i < 8; ++i) {                  // rows rg, rg+2, ..., rg+14
        float4 x = src[(size_t)(rg + 2 * i) * (DIM / 4) + f4];
        s.x += x.x; s.y += x.y; s.z += x.z; s.w += x.w;
    }
    red[t] = s;
    __syncthreads();
    if (t < 128) {
        float4 a = red[t], c = red[t + 128];
        partial[(size_t)blk * (DIM / 4) + t] =
            make_float4(a.x + c.x, a.y + c.y, a.z + c.z, a.w + c.w);
    }
}

// ---- K2: 32 blocks = b(4) x sl(8). Reduce csum[b] block-locally, compute
// vsum e-slice (64 e), then its orow contribution opart[sl][b][:512]. ----
__global__ __launch_bounds__(256) void k2_middle(const float4* __restrict__ partial,
                                                 const float* __restrict__ Wkv,
                                                 const float* __restrict__ Wout,
                                                 float* __restrict__ opart) {
    __shared__ float4 red[256];     // 4 KB
    __shared__ float cs[DIM];       // csum for this batch
    __shared__ float vl[256];       // matvec partials
    __shared__ float vslice[64];    // vsum slice
    const int blk = blockIdx.x, t = threadIdx.x;
    const int b1 = blk >> 3, sl = blk & 7;

    // csum: reduce 128 chunk partials (256 KB, L2-hot). g = float4 col, h = half
    {
        const int g = t & 127, h = t >> 7;
        const float4* p = partial + (size_t)(b1 * CPB + h * 64) * (DIM / 4) + g;
        float4 s = make_float4(0.f, 0.f, 0.f, 0.f);
#pragma unroll 16
        for (int j = 0; j < 64; ++j) {
            float4 x = p[(size_t)j * (DIM / 4)];
            s.x += x.x; s.y += x.y; s.z += x.z; s.w += x.w;
        }
        red[t] = s;
    }
    __syncthreads();
    if (t < 128) {
        float4 a = red[t], c = red[t + 128];
        reinterpret_cast<float4*>(cs)[t] =
            make_float4(a.x + c.x, a.y + c.y, a.z + c.z, a.w + c.w);
    }
    __syncthreads();

    // vsum slice: e = sl*64 + (t&63), partial over d-range dg*128..+128
    {
        const int el = t & 63, dg = t >> 6;
        const float* w = Wkv + (size_t)(dg * 128) * (2 * DIM) + DIM + sl * 64 + el;
        float s = 0.f;
#pragma unroll 8
        for (int d0 = 0; d0 < 128; ++d0)
            s += cs[dg * 128 + d0] * w[(size_t)d0 * (2 * DIM)];
        vl[t] = s;
    }
    __syncthreads();
    if (t < 64) vslice[t] = vl[t] + vl[t + 64] + vl[t + 128] + vl[t + 192];
    __syncthreads();

    // orow contribution: opart[sl][b1][f] = sum_e vslice[e] * Wout[sl*64+e][f]
    {
#pragma unroll
        for (int half = 0; half < 2; ++half) {
            const int f = half * 256 + t;
            const float* w = Wout + (size_t)(sl * 64) * DIM + f;
            float s = 0.f;
#pragma unroll 8
            for (int e0 = 0; e0 < 64; ++e0)
                s += vslice[e0] * w[(size_t)e0 * DIM];
            opart[(size_t)(sl * BATCH + b1) * DIM + f] = s;
        }
    }
}

// ---- K3: out[b,q,:] = sum_sl opart[sl][b][:] for all q (16.8 MB write) ----
__global__ __launch_bounds__(256) void k3_bcast(const float4* __restrict__ opart4,
                                                float4* __restrict__ out) {
    const int blk = blockIdx.x, t = threadIdx.x;
    const int b = blk >> 8, qg = blk & 255;
    const int rg = t >> 7, f4 = t & 127;
    float4 v = make_float4(0.f, 0.f, 0.f, 0.f);
#pragma unroll
    for (int sl = 0; sl < NSL; ++sl) {             // 8 L2-hot loads, independent
        float4 x = opart4[(size_t)(sl * BATCH + b) * (DIM / 4) + f4];
        v.x += x.x; v.y += x.y; v.z += x.z; v.w += x.w;
    }
    float4* dst = out + (size_t)(b * QLEN + qg * 8) * (DIM / 4);
#pragma unroll
    for (int i = 0; i < 4; ++i)                    // rows rg, rg+2, rg+4, rg+6
        dst[(size_t)(rg + 2 * i) * (DIM / 4) + f4] = v;
}

extern "C" void kernel_launch(void* const* d_in, const int* in_sizes, int n_in,
                              void* d_out, int out_size, void* d_ws, size_t ws_size,
                              hipStream_t stream) {
    // inputs: 0=query (unused), 1=context, 2=mask (unused), 3=Wq (unused), 4=Wkv, 5=Wout
    const float* ctx  = (const float*)d_in[1];
    const float* Wkv  = (const float*)d_in[4];
    const float* Wout = (const float*)d_in[5];
    float* ws = (float*)d_ws;
    float* partial = ws;                                   // NBLK1*DIM = 1 MB
    float* opart   = partial + (size_t)NBLK1 * DIM;        // NSL*BATCH*DIM = 64 KB
    // no memset: every ws word is written before it is read

    k1_partial<<<NBLK1, 256, 0, stream>>>(ctx, (float4*)partial);
    k2_middle<<<BATCH * NSL, 256, 0, stream>>>((const float4*)partial, Wkv, Wout, opart);
    k3_bcast<<<BATCH * 256, 256, 0, stream>>>((const float4*)opart, (float4*)d_out);
}